// Round 5
// baseline (883.434 us; speedup 1.0000x reference)
//
#include <hip/hip_runtime.h>
#include <hip/hip_fp16.h>
#include <math.h>

// GCN 2-layer, fp32 compute. Round 5:
//  - gemm1: K-sliced LDS staging (17 KB vs 50 KB -> 9 blocks/CU, was 3)
//  - h1 stored fp16 (halves agg1's 410 MB logical gather; error budget ~2e-4)
//  - p2: unrolled column scan (batch the dependent global loads)

constexpr int N_NODES = 100000;
constexpr int N_EDGES = 1600000;
constexpr int IN_F    = 128;
constexpr int HID     = 64;
constexpr int NC      = 16;

constexpr int NBLK_P  = 128;                 // partition blocks
constexpr int EPB     = N_EDGES / NBLK_P;    // 12500 edges per partition block
constexpr int NB_D    = 391;                 // dst buckets (256 nodes each)
constexpr int NB_ALL  = 2 * NB_D;            // 782: [0,391) dst, [391,782) src

// ---------------- p1: per-block bucket histogram (both keys) ----------------
__global__ __launch_bounds__(256) void k_p1(const int* __restrict__ src,
                                            const int* __restrict__ dst,
                                            int* __restrict__ gHist) {
    __shared__ int hist[NB_ALL];
    const int t = threadIdx.x, b = blockIdx.x;
    for (int i = t; i < NB_ALL; i += 256) hist[i] = 0;
    __syncthreads();
    const int beg = b * EPB, end = beg + EPB;
    for (int i = beg + t; i < end; i += 256) {
        atomicAdd(&hist[dst[i] >> 8], 1);
        atomicAdd(&hist[NB_D + (src[i] >> 8)], 1);
    }
    __syncthreads();
    for (int i = t; i < NB_ALL; i += 256)
        gHist[b * NB_ALL + i] = hist[i];     // coalesced
}

// ---------------- p2: column scan -> cursors (in place) + bucket starts ------
__global__ __launch_bounds__(1024) void k_p2(int* __restrict__ gHist,
                                             int* __restrict__ bucketStart) {
    const int t = threadIdx.x;               // 1024 threads, 782 active columns
    int total = 0;
    if (t < NB_ALL) {
        #pragma unroll 8
        for (int blk = 0; blk < NBLK_P; ++blk) {
            int idx = blk * NB_ALL + t;      // coalesced across threads
            int v = gHist[idx];
            gHist[idx] = total;              // local exclusive prefix
            total += v;
        }
    }
    int v = total;
    int lane = t & 63, wid = t >> 6;
    #pragma unroll
    for (int d = 1; d < 64; d <<= 1) { int u = __shfl_up(v, d, 64); if (lane >= d) v += u; }
    __shared__ int wsum[16];
    if (lane == 63) wsum[wid] = v;
    __syncthreads();
    int woff = 0;
    for (int w = 0; w < wid; ++w) woff += wsum[w];
    int colStart = woff + v - total;         // exclusive
    if (t < NB_ALL) {
        bucketStart[t] = colStart;
        if (t == NB_ALL - 1) bucketStart[NB_ALL] = colStart + total;  // = 2E
        #pragma unroll 8
        for (int blk = 0; blk < NBLK_P; ++blk)
            gHist[blk * NB_ALL + t] += colStart;   // now global cursors
    }
}

// ---------------- p3: scatter edges into buckets (LDS cursors) ----------------
__global__ __launch_bounds__(256) void k_p3(const int* __restrict__ src,
                                            const int* __restrict__ dst,
                                            const int* __restrict__ gCursor,
                                            unsigned int* __restrict__ ebufD,
                                            unsigned char* __restrict__ ebufS) {
    __shared__ int curs[NB_ALL];
    const int t = threadIdx.x, b = blockIdx.x;
    for (int i = t; i < NB_ALL; i += 256) curs[i] = gCursor[b * NB_ALL + i];
    __syncthreads();
    const int beg = b * EPB, end = beg + EPB;
    for (int i = beg + t; i < end; i += 256) {
        int d = dst[i], s = src[i];
        int pD = atomicAdd(&curs[d >> 8], 1);
        ebufD[pD] = ((unsigned)(d & 255) << 17) | (unsigned)s;
        int pS = atomicAdd(&curs[NB_D + (s >> 8)], 1);
        ebufS[pS - N_EDGES] = (unsigned char)(s & 255);
    }
}

// ---------------- bcsr: per-bucket CSR build + norm_dst + row_start ----------
__global__ __launch_bounds__(256) void k_bcsr(const int* __restrict__ bucketStart,
                                              const unsigned int* __restrict__ ebufD,
                                              int* __restrict__ row_start,
                                              float* __restrict__ norm_dst,
                                              int* __restrict__ csr_src) {
    __shared__ int cnt[256];
    __shared__ int curs[256];
    __shared__ int wsum[4];
    const int t = threadIdx.x, b = blockIdx.x;
    const int beg = bucketStart[b], end = bucketStart[b + 1];
    cnt[t] = 0;
    __syncthreads();
    for (int i = beg + t; i < end; i += 256)
        atomicAdd(&cnt[ebufD[i] >> 17], 1);
    __syncthreads();
    int x = cnt[t];
    int v = x;
    int lane = t & 63, wid = t >> 6;
    #pragma unroll
    for (int d = 1; d < 64; d <<= 1) { int u = __shfl_up(v, d, 64); if (lane >= d) v += u; }
    if (lane == 63) wsum[wid] = v;
    __syncthreads();
    int woff = 0;
    for (int w = 0; w < wid; ++w) woff += wsum[w];
    int rs = woff + v - x;                   // exclusive prefix
    int node = b * 256 + t;
    if (node <= N_NODES) row_start[node] = beg + rs;
    if (node <  N_NODES) norm_dst[node] = 1.0f / sqrtf(fmaxf((float)x, 1.0f));
    curs[t] = beg + rs;
    __syncthreads();
    for (int i = beg + t; i < end; i += 256) {
        unsigned int e = ebufD[i];
        int pos = atomicAdd(&curs[e >> 17], 1);
        csr_src[pos] = (int)(e & 0x1FFFFu);
    }
}

// ---------------- bdeg: per-bucket src counts -> norm_src ----------------
__global__ __launch_bounds__(256) void k_bdeg(const int* __restrict__ bucketStart,
                                              const unsigned char* __restrict__ ebufS,
                                              float* __restrict__ norm_src) {
    __shared__ int cnt[256];
    const int t = threadIdx.x, b = blockIdx.x;
    const int beg = bucketStart[NB_D + b] - N_EDGES;
    const int end = bucketStart[NB_D + b + 1] - N_EDGES;
    cnt[t] = 0;
    __syncthreads();
    for (int i = beg + t; i < end; i += 256)
        atomicAdd(&cnt[ebufS[i]], 1);
    __syncthreads();
    int node = b * 256 + t;
    if (node < N_NODES)
        norm_src[node] = 1.0f / sqrtf(fmaxf((float)cnt[t], 1.0f));
}

#define GEMM_STEP(accr, xvr) \
    accr.x += xvr.x*w0.x + xvr.y*w1.x + xvr.z*w2.x + xvr.w*w3.x; \
    accr.y += xvr.x*w0.y + xvr.y*w1.y + xvr.z*w2.y + xvr.w*w3.y; \
    accr.z += xvr.x*w0.z + xvr.y*w1.z + xvr.z*w2.z + xvr.w*w3.z; \
    accr.w += xvr.x*w0.w + xvr.y*w1.w + xvr.z*w2.w + xvr.w*w3.w;

// ---------------- GEMM1: 64x64 tile, K-sliced staging (32 per slice) ---------
// LDS: Ws slice 8 KB + xs slice 9.2 KB = 17.2 KB -> 9 blocks/CU.
// Output h1 stored as fp16.
__global__ __launch_bounds__(256) void k_gemm1(
        const float* __restrict__ x, const float* __restrict__ W1,
        const float* __restrict__ norm_src, __half* __restrict__ h1h) {
    __shared__ float Ws[32 * HID];       // 8 KB, no pad (2-way banks on read = free)
    __shared__ float xs[64 * 36];        // 9.2 KB, stride 36 -> 2-way banks (free)
    const int t = threadIdx.x;
    const int cg = t & 15;               // cols cg*4..+3
    const int rg = t >> 4;               // rows rg*4..+3
    const int row0 = blockIdx.x * 64;
    float4 acc0 = {0,0,0,0}, acc1 = {0,0,0,0}, acc2 = {0,0,0,0}, acc3 = {0,0,0,0};
    #pragma unroll
    for (int kh = 0; kh < 4; ++kh) {     // 4 K-slices of 32
        __syncthreads();
        // stage x slice: 64 rows x 32 ks = 512 float4, 2 per thread
        #pragma unroll
        for (int i = t; i < 512; i += 256) {
            int rr = i >> 3, cc = i & 7;
            int gr = row0 + rr;
            float4 v = (gr < N_NODES)
                ? *(const float4*)&x[(size_t)gr * IN_F + kh * 32 + cc * 4]
                : float4{0.f, 0.f, 0.f, 0.f};
            *(float4*)&xs[rr * 36 + cc * 4] = v;
        }
        // stage W slice: 32 ks x 64 cols = 512 float4, 2 per thread
        #pragma unroll
        for (int i = t; i < 512; i += 256) {
            int kr = i >> 4, kc = i & 15;
            *(float4*)&Ws[kr * HID + kc * 4] =
                *(const float4*)&W1[(size_t)(kh * 32 + kr) * HID + kc * 4];
        }
        __syncthreads();
        #pragma unroll
        for (int k = 0; k < 32; k += 4) {
            float4 xv0 = *(float4*)&xs[(rg * 4 + 0) * 36 + k];
            float4 xv1 = *(float4*)&xs[(rg * 4 + 1) * 36 + k];
            float4 xv2 = *(float4*)&xs[(rg * 4 + 2) * 36 + k];
            float4 xv3 = *(float4*)&xs[(rg * 4 + 3) * 36 + k];
            float4 w0 = *(float4*)&Ws[(k + 0) * HID + cg * 4];
            float4 w1 = *(float4*)&Ws[(k + 1) * HID + cg * 4];
            float4 w2 = *(float4*)&Ws[(k + 2) * HID + cg * 4];
            float4 w3 = *(float4*)&Ws[(k + 3) * HID + cg * 4];
            GEMM_STEP(acc0, xv0)
            GEMM_STEP(acc1, xv1)
            GEMM_STEP(acc2, xv2)
            GEMM_STEP(acc3, xv3)
        }
    }
    const int r0 = row0 + rg * 4;
    #pragma unroll
    for (int r = 0; r < 4; ++r) {
        int rr = r0 + r;
        if (rr < N_NODES) {
            float4 a = (r == 0) ? acc0 : (r == 1) ? acc1 : (r == 2) ? acc2 : acc3;
            float ns = norm_src[rr];
            float2 pk;
            *(__half2*)&pk.x = __floats2half2_rn(a.x * ns, a.y * ns);
            *(__half2*)&pk.y = __floats2half2_rn(a.z * ns, a.w * ns);
            *(float2*)&h1h[(size_t)rr * HID + cg * 4] = pk;   // 8B store
        }
    }
}

// ---------------- agg1: 16 lanes/node, fp16 gathers, 8-edge unroll -----------
__global__ __launch_bounds__(256) void k_agg1(
        const int* __restrict__ row_start, const int* __restrict__ csr_src,
        const __half* __restrict__ h1h, const float* __restrict__ nd,
        const float* __restrict__ b1, float* __restrict__ h1r) {
    int node = blockIdx.x * 16 + (threadIdx.x >> 4);
    int q = threadIdx.x & 15;            // feat quad
    if (node >= N_NODES) return;
    int beg = row_start[node], end = row_start[node + 1];
    float4 acc = {0.f, 0.f, 0.f, 0.f};
    int p = beg;
    for (; p + 8 <= end; p += 8) {
        float2 g[8];
        #pragma unroll
        for (int u = 0; u < 8; ++u) {
            int s = csr_src[p + u];
            g[u] = *(const float2*)&h1h[(size_t)s * HID + q * 4];
        }
        #pragma unroll
        for (int u = 0; u < 8; ++u) {
            float2 f0 = __half22float2(*(__half2*)&g[u].x);
            float2 f1 = __half22float2(*(__half2*)&g[u].y);
            acc.x += f0.x; acc.y += f0.y; acc.z += f1.x; acc.w += f1.y;
        }
    }
    for (; p < end; ++p) {
        int s = csr_src[p];
        float2 raw = *(const float2*)&h1h[(size_t)s * HID + q * 4];
        float2 f0 = __half22float2(*(__half2*)&raw.x);
        float2 f1 = __half22float2(*(__half2*)&raw.y);
        acc.x += f0.x; acc.y += f0.y; acc.z += f1.x; acc.w += f1.y;
    }
    float n = nd[node];
    float4 bb = *(const float4*)&b1[q * 4];
    float4 o;
    o.x = fmaxf(acc.x * n + bb.x, 0.f);
    o.y = fmaxf(acc.y * n + bb.y, 0.f);
    o.z = fmaxf(acc.z * n + bb.z, 0.f);
    o.w = fmaxf(acc.w * n + bb.w, 0.f);
    *(float4*)&h1r[(size_t)node * HID + q * 4] = o;
}

// ---------------- GEMM2: 64-row tiles ----------------
__global__ __launch_bounds__(256) void k_gemm2(
        const float* __restrict__ hin, const float* __restrict__ W2,
        const float* __restrict__ norm_src, float* __restrict__ h2) {
    __shared__ float Ws[HID * NC];          // 4 KB
    __shared__ float xs[64 * 68];           // stride 68 -> 2-way banks (free)
    const int t = threadIdx.x;
    for (int i = t * 4; i < HID * NC; i += 256 * 4)
        *(float4*)&Ws[i] = *(const float4*)&W2[i];
    const int jq = t & 3;
    const int rl = t >> 2;
    const int row0 = blockIdx.x * 64;
    __syncthreads();
    for (int i = t; i < 64 * (HID / 4); i += 256) {
        int rr = i >> 4, cc = i & 15;
        int gr = row0 + rr;
        float4 v = (gr < N_NODES) ? *(const float4*)&hin[(size_t)gr * HID + cc * 4]
                                  : float4{0.f, 0.f, 0.f, 0.f};
        *(float4*)&xs[rr * 68 + cc * 4] = v;
    }
    __syncthreads();
    int r = row0 + rl;
    if (r < N_NODES) {
        float4 acc = {0.f, 0.f, 0.f, 0.f};
        #pragma unroll
        for (int k = 0; k < HID; k += 4) {
            float4 xv = *(float4*)&xs[rl * 68 + k];
            float4 w0 = *(float4*)&Ws[(k + 0) * NC + jq * 4];
            float4 w1 = *(float4*)&Ws[(k + 1) * NC + jq * 4];
            float4 w2 = *(float4*)&Ws[(k + 2) * NC + jq * 4];
            float4 w3 = *(float4*)&Ws[(k + 3) * NC + jq * 4];
            GEMM_STEP(acc, xv)
        }
        float ns = norm_src[r];
        acc.x *= ns; acc.y *= ns; acc.z *= ns; acc.w *= ns;
        *(float4*)&h2[(size_t)r * NC + jq * 4] = acc;
    }
}

// ---------------- agg2 + softmax: 4 lanes/node, float4, 4-edge unroll --------
__global__ __launch_bounds__(256) void k_agg2(
        const int* __restrict__ row_start, const int* __restrict__ csr_src,
        const float* __restrict__ h2, const float* __restrict__ nd,
        const float* __restrict__ b2, float* __restrict__ out) {
    int t = threadIdx.x;
    int node = blockIdx.x * 64 + (t >> 2);
    int sub = t & 3;                     // feats sub*4..+3
    if (node >= N_NODES) return;
    int beg = row_start[node], end = row_start[node + 1];
    float4 acc = {0.f, 0.f, 0.f, 0.f};
    int p = beg;
    for (; p + 4 <= end; p += 4) {
        int s0 = csr_src[p + 0], s1 = csr_src[p + 1];
        int s2 = csr_src[p + 2], s3 = csr_src[p + 3];
        float4 a0 = *(const float4*)&h2[(size_t)s0 * NC + sub * 4];
        float4 a1 = *(const float4*)&h2[(size_t)s1 * NC + sub * 4];
        float4 a2 = *(const float4*)&h2[(size_t)s2 * NC + sub * 4];
        float4 a3 = *(const float4*)&h2[(size_t)s3 * NC + sub * 4];
        acc.x += a0.x + a1.x + a2.x + a3.x;
        acc.y += a0.y + a1.y + a2.y + a3.y;
        acc.z += a0.z + a1.z + a2.z + a3.z;
        acc.w += a0.w + a1.w + a2.w + a3.w;
    }
    for (; p < end; ++p) {
        int s = csr_src[p];
        float4 a = *(const float4*)&h2[(size_t)s * NC + sub * 4];
        acc.x += a.x; acc.y += a.y; acc.z += a.z; acc.w += a.w;
    }
    float n = nd[node];
    float4 bb = *(const float4*)&b2[sub * 4];
    float4 vv;
    vv.x = acc.x * n + bb.x;
    vv.y = acc.y * n + bb.y;
    vv.z = acc.z * n + bb.z;
    vv.w = acc.w * n + bb.w;
    float m = fmaxf(fmaxf(vv.x, vv.y), fmaxf(vv.z, vv.w));
    m = fmaxf(m, __shfl_xor(m, 1, 4));
    m = fmaxf(m, __shfl_xor(m, 2, 4));
    float e0 = __expf(vv.x - m), e1 = __expf(vv.y - m);
    float e2 = __expf(vv.z - m), e3 = __expf(vv.w - m);
    float s = e0 + e1 + e2 + e3;
    s += __shfl_xor(s, 1, 4);
    s += __shfl_xor(s, 2, 4);
    float inv = 1.0f / s;
    float4 o = { e0 * inv, e1 * inv, e2 * inv, e3 * inv };
    *(float4*)&out[(size_t)node * NC + sub * 4] = o;
}

extern "C" void kernel_launch(void* const* d_in, const int* in_sizes, int n_in,
                              void* d_out, int out_size, void* d_ws, size_t ws_size,
                              hipStream_t stream) {
    const float* x   = (const float*)d_in[0];
    const int*   src = (const int*)  d_in[1];
    const int*   dst = (const int*)  d_in[2];
    const float* W1  = (const float*)d_in[3];
    const float* b1  = (const float*)d_in[4];
    const float* W2  = (const float*)d_in[5];
    const float* b2  = (const float*)d_in[6];
    float* out = (float*)d_out;

    // ws layout (4-byte words), N=100000, E=1.6M:
    //   [0,N) norm_src | [N,2N) norm_dst
    //   [2N,34N)   h1 fp16 (64N halves); h2 fp32 (16N) aliases after agg1
    //   [66N,130N) h1r fp32; ebufD (E words)+ebufS (E bytes) alias before agg1
    //   [130N,131N] row_start (N+1)
    //   [131N+8 ..)  bucketStart | gHist | csr_src
    const size_t N = N_NODES;
    float* ws       = (float*)d_ws;
    int*   wsI      = (int*)d_ws;
    float* norm_src = ws;
    float* norm_dst = ws + N;
    __half* h1h     = (__half*)(ws + 2 * N);   // 64N halves = 32N words
    float* h2       = ws + 2 * N;              // alias (h1 dead after agg1)
    float* h1r      = ws + 66 * N;
    unsigned int*  ebufD = (unsigned int*)(wsI + 66 * N);            // E words
    unsigned char* ebufS = (unsigned char*)(wsI + 66 * N + N_EDGES); // E bytes
    int*   row_st   = wsI + 130 * N;
    int*   bstart   = wsI + 131 * N + 8;
    int*   gHist    = wsI + 131 * N + 800;
    int*   csr_src  = wsI + 131 * N + 800 + NBLK_P * NB_ALL;

    k_p1  <<<NBLK_P, 256, 0, stream>>>(src, dst, gHist);
    k_p2  <<<1, 1024, 0, stream>>>(gHist, bstart);
    k_p3  <<<NBLK_P, 256, 0, stream>>>(src, dst, gHist, ebufD, ebufS);
    k_bcsr<<<NB_D, 256, 0, stream>>>(bstart, ebufD, row_st, norm_dst, csr_src);
    k_bdeg<<<NB_D, 256, 0, stream>>>(bstart, ebufS, norm_src);
    k_gemm1<<<(N_NODES + 63) / 64, 256, 0, stream>>>(x, W1, norm_src, h1h);
    k_agg1<<<(N_NODES + 15) / 16, 256, 0, stream>>>(row_st, csr_src, h1h,
                                                    norm_dst, b1, h1r);
    k_gemm2<<<(N_NODES + 63) / 64, 256, 0, stream>>>(h1r, W2, norm_src, h2);
    k_agg2<<<(N_NODES + 63) / 64, 256, 0, stream>>>(row_st, csr_src, h2,
                                                    norm_dst, b2, out);
}

// Round 6
// 361.191 us; speedup vs baseline: 2.4459x; 2.4459x over previous
//
#include <hip/hip_runtime.h>
#include <hip/hip_fp16.h>
#include <math.h>

// GCN 2-layer, fp32 compute. Round 6: round-5 structure with the gemm1
// register-spill fixed (#pragma unroll 1 on the K-slice loop + launch_bounds
// VGPR cap at 128). h1 stored fp16 (error budget verified in R5: absmax 4.9e-4).

constexpr int N_NODES = 100000;
constexpr int N_EDGES = 1600000;
constexpr int IN_F    = 128;
constexpr int HID     = 64;
constexpr int NC      = 16;

constexpr int NBLK_P  = 128;                 // partition blocks
constexpr int EPB     = N_EDGES / NBLK_P;    // 12500 edges per partition block
constexpr int NB_D    = 391;                 // dst buckets (256 nodes each)
constexpr int NB_ALL  = 2 * NB_D;            // 782: [0,391) dst, [391,782) src

// ---------------- p1: per-block bucket histogram (both keys) ----------------
__global__ __launch_bounds__(256) void k_p1(const int* __restrict__ src,
                                            const int* __restrict__ dst,
                                            int* __restrict__ gHist) {
    __shared__ int hist[NB_ALL];
    const int t = threadIdx.x, b = blockIdx.x;
    for (int i = t; i < NB_ALL; i += 256) hist[i] = 0;
    __syncthreads();
    const int beg = b * EPB, end = beg + EPB;
    for (int i = beg + t; i < end; i += 256) {
        atomicAdd(&hist[dst[i] >> 8], 1);
        atomicAdd(&hist[NB_D + (src[i] >> 8)], 1);
    }
    __syncthreads();
    for (int i = t; i < NB_ALL; i += 256)
        gHist[b * NB_ALL + i] = hist[i];     // coalesced
}

// ---------------- p2: column scan -> cursors (in place) + bucket starts ------
__global__ __launch_bounds__(1024) void k_p2(int* __restrict__ gHist,
                                             int* __restrict__ bucketStart) {
    const int t = threadIdx.x;               // 1024 threads, 782 active columns
    int total = 0;
    if (t < NB_ALL) {
        #pragma unroll 8
        for (int blk = 0; blk < NBLK_P; ++blk) {
            int idx = blk * NB_ALL + t;      // coalesced across threads
            int v = gHist[idx];
            gHist[idx] = total;              // local exclusive prefix
            total += v;
        }
    }
    int v = total;
    int lane = t & 63, wid = t >> 6;
    #pragma unroll
    for (int d = 1; d < 64; d <<= 1) { int u = __shfl_up(v, d, 64); if (lane >= d) v += u; }
    __shared__ int wsum[16];
    if (lane == 63) wsum[wid] = v;
    __syncthreads();
    int woff = 0;
    for (int w = 0; w < wid; ++w) woff += wsum[w];
    int colStart = woff + v - total;         // exclusive
    if (t < NB_ALL) {
        bucketStart[t] = colStart;
        if (t == NB_ALL - 1) bucketStart[NB_ALL] = colStart + total;  // = 2E
        #pragma unroll 8
        for (int blk = 0; blk < NBLK_P; ++blk)
            gHist[blk * NB_ALL + t] += colStart;   // now global cursors
    }
}

// ---------------- p3: scatter edges into buckets (LDS cursors) ----------------
__global__ __launch_bounds__(256) void k_p3(const int* __restrict__ src,
                                            const int* __restrict__ dst,
                                            const int* __restrict__ gCursor,
                                            unsigned int* __restrict__ ebufD,
                                            unsigned char* __restrict__ ebufS) {
    __shared__ int curs[NB_ALL];
    const int t = threadIdx.x, b = blockIdx.x;
    for (int i = t; i < NB_ALL; i += 256) curs[i] = gCursor[b * NB_ALL + i];
    __syncthreads();
    const int beg = b * EPB, end = beg + EPB;
    for (int i = beg + t; i < end; i += 256) {
        int d = dst[i], s = src[i];
        int pD = atomicAdd(&curs[d >> 8], 1);
        ebufD[pD] = ((unsigned)(d & 255) << 17) | (unsigned)s;
        int pS = atomicAdd(&curs[NB_D + (s >> 8)], 1);
        ebufS[pS - N_EDGES] = (unsigned char)(s & 255);
    }
}

// ---------------- bcsr: per-bucket CSR build + norm_dst + row_start ----------
__global__ __launch_bounds__(256) void k_bcsr(const int* __restrict__ bucketStart,
                                              const unsigned int* __restrict__ ebufD,
                                              int* __restrict__ row_start,
                                              float* __restrict__ norm_dst,
                                              int* __restrict__ csr_src) {
    __shared__ int cnt[256];
    __shared__ int curs[256];
    __shared__ int wsum[4];
    const int t = threadIdx.x, b = blockIdx.x;
    const int beg = bucketStart[b], end = bucketStart[b + 1];
    cnt[t] = 0;
    __syncthreads();
    for (int i = beg + t; i < end; i += 256)
        atomicAdd(&cnt[ebufD[i] >> 17], 1);
    __syncthreads();
    int x = cnt[t];
    int v = x;
    int lane = t & 63, wid = t >> 6;
    #pragma unroll
    for (int d = 1; d < 64; d <<= 1) { int u = __shfl_up(v, d, 64); if (lane >= d) v += u; }
    if (lane == 63) wsum[wid] = v;
    __syncthreads();
    int woff = 0;
    for (int w = 0; w < wid; ++w) woff += wsum[w];
    int rs = woff + v - x;                   // exclusive prefix
    int node = b * 256 + t;
    if (node <= N_NODES) row_start[node] = beg + rs;
    if (node <  N_NODES) norm_dst[node] = 1.0f / sqrtf(fmaxf((float)x, 1.0f));
    curs[t] = beg + rs;
    __syncthreads();
    for (int i = beg + t; i < end; i += 256) {
        unsigned int e = ebufD[i];
        int pos = atomicAdd(&curs[e >> 17], 1);
        csr_src[pos] = (int)(e & 0x1FFFFu);
    }
}

// ---------------- bdeg: per-bucket src counts -> norm_src ----------------
__global__ __launch_bounds__(256) void k_bdeg(const int* __restrict__ bucketStart,
                                              const unsigned char* __restrict__ ebufS,
                                              float* __restrict__ norm_src) {
    __shared__ int cnt[256];
    const int t = threadIdx.x, b = blockIdx.x;
    const int beg = bucketStart[NB_D + b] - N_EDGES;
    const int end = bucketStart[NB_D + b + 1] - N_EDGES;
    cnt[t] = 0;
    __syncthreads();
    for (int i = beg + t; i < end; i += 256)
        atomicAdd(&cnt[ebufS[i]], 1);
    __syncthreads();
    int node = b * 256 + t;
    if (node < N_NODES)
        norm_src[node] = 1.0f / sqrtf(fmaxf((float)cnt[t], 1.0f));
}

#define GEMM_STEP(accr, xvr) \
    accr.x += xvr.x*w0.x + xvr.y*w1.x + xvr.z*w2.x + xvr.w*w3.x; \
    accr.y += xvr.x*w0.y + xvr.y*w1.y + xvr.z*w2.y + xvr.w*w3.y; \
    accr.z += xvr.x*w0.z + xvr.y*w1.z + xvr.z*w2.z + xvr.w*w3.z; \
    accr.w += xvr.x*w0.w + xvr.y*w1.w + xvr.z*w2.w + xvr.w*w3.w;

// ---------------- GEMM1: 64x64 tile, K-sliced staging (32 per slice) ---------
// LDS 17.2 KB; kh loop NOT unrolled (R5 postmortem: full unroll -> 256 VGPR +
// 800 MB scratch spill). launch_bounds(,4) caps allocator at 128 VGPR.
__global__ __launch_bounds__(256, 4) void k_gemm1(
        const float* __restrict__ x, const float* __restrict__ W1,
        const float* __restrict__ norm_src, __half* __restrict__ h1h) {
    __shared__ float Ws[32 * HID];       // 8 KB
    __shared__ float xs[64 * 36];        // 9.2 KB, stride 36 -> 2-way banks (free)
    const int t = threadIdx.x;
    const int cg = t & 15;               // cols cg*4..+3
    const int rg = t >> 4;               // rows rg*4..+3
    const int row0 = blockIdx.x * 64;
    float4 acc0 = {0,0,0,0}, acc1 = {0,0,0,0}, acc2 = {0,0,0,0}, acc3 = {0,0,0,0};
    #pragma unroll 1
    for (int kh = 0; kh < 4; ++kh) {     // 4 K-slices of 32
        __syncthreads();
        for (int i = t; i < 512; i += 256) {          // x slice: 64r x 32k
            int rr = i >> 3, cc = i & 7;
            int gr = row0 + rr;
            float4 v = (gr < N_NODES)
                ? *(const float4*)&x[(size_t)gr * IN_F + kh * 32 + cc * 4]
                : float4{0.f, 0.f, 0.f, 0.f};
            *(float4*)&xs[rr * 36 + cc * 4] = v;
        }
        for (int i = t; i < 512; i += 256) {          // W slice: 32k x 64c
            int kr = i >> 4, kc = i & 15;
            *(float4*)&Ws[kr * HID + kc * 4] =
                *(const float4*)&W1[(size_t)(kh * 32 + kr) * HID + kc * 4];
        }
        __syncthreads();
        #pragma unroll
        for (int k = 0; k < 32; k += 4) {
            float4 xv0 = *(float4*)&xs[(rg * 4 + 0) * 36 + k];
            float4 xv1 = *(float4*)&xs[(rg * 4 + 1) * 36 + k];
            float4 xv2 = *(float4*)&xs[(rg * 4 + 2) * 36 + k];
            float4 xv3 = *(float4*)&xs[(rg * 4 + 3) * 36 + k];
            float4 w0 = *(float4*)&Ws[(k + 0) * HID + cg * 4];
            float4 w1 = *(float4*)&Ws[(k + 1) * HID + cg * 4];
            float4 w2 = *(float4*)&Ws[(k + 2) * HID + cg * 4];
            float4 w3 = *(float4*)&Ws[(k + 3) * HID + cg * 4];
            GEMM_STEP(acc0, xv0)
            GEMM_STEP(acc1, xv1)
            GEMM_STEP(acc2, xv2)
            GEMM_STEP(acc3, xv3)
        }
    }
    const int r0 = row0 + rg * 4;
    #pragma unroll
    for (int r = 0; r < 4; ++r) {
        int rr = r0 + r;
        if (rr < N_NODES) {
            float4 a = (r == 0) ? acc0 : (r == 1) ? acc1 : (r == 2) ? acc2 : acc3;
            float ns = norm_src[rr];
            float2 pk;
            *(__half2*)&pk.x = __floats2half2_rn(a.x * ns, a.y * ns);
            *(__half2*)&pk.y = __floats2half2_rn(a.z * ns, a.w * ns);
            *(float2*)&h1h[(size_t)rr * HID + cg * 4] = pk;   // 8B store
        }
    }
}

// ---------------- agg1: 16 lanes/node, fp16 gathers, 8-edge unroll -----------
__global__ __launch_bounds__(256) void k_agg1(
        const int* __restrict__ row_start, const int* __restrict__ csr_src,
        const __half* __restrict__ h1h, const float* __restrict__ nd,
        const float* __restrict__ b1, float* __restrict__ h1r) {
    int node = blockIdx.x * 16 + (threadIdx.x >> 4);
    int q = threadIdx.x & 15;            // feat quad
    if (node >= N_NODES) return;
    int beg = row_start[node], end = row_start[node + 1];
    float4 acc = {0.f, 0.f, 0.f, 0.f};
    int p = beg;
    for (; p + 8 <= end; p += 8) {
        float2 g[8];
        #pragma unroll
        for (int u = 0; u < 8; ++u) {
            int s = csr_src[p + u];
            g[u] = *(const float2*)&h1h[(size_t)s * HID + q * 4];
        }
        #pragma unroll
        for (int u = 0; u < 8; ++u) {
            float2 f0 = __half22float2(*(__half2*)&g[u].x);
            float2 f1 = __half22float2(*(__half2*)&g[u].y);
            acc.x += f0.x; acc.y += f0.y; acc.z += f1.x; acc.w += f1.y;
        }
    }
    for (; p < end; ++p) {
        int s = csr_src[p];
        float2 raw = *(const float2*)&h1h[(size_t)s * HID + q * 4];
        float2 f0 = __half22float2(*(__half2*)&raw.x);
        float2 f1 = __half22float2(*(__half2*)&raw.y);
        acc.x += f0.x; acc.y += f0.y; acc.z += f1.x; acc.w += f1.y;
    }
    float n = nd[node];
    float4 bb = *(const float4*)&b1[q * 4];
    float4 o;
    o.x = fmaxf(acc.x * n + bb.x, 0.f);
    o.y = fmaxf(acc.y * n + bb.y, 0.f);
    o.z = fmaxf(acc.z * n + bb.z, 0.f);
    o.w = fmaxf(acc.w * n + bb.w, 0.f);
    *(float4*)&h1r[(size_t)node * HID + q * 4] = o;
}

// ---------------- GEMM2: 64-row tiles ----------------
__global__ __launch_bounds__(256) void k_gemm2(
        const float* __restrict__ hin, const float* __restrict__ W2,
        const float* __restrict__ norm_src, float* __restrict__ h2) {
    __shared__ float Ws[HID * NC];          // 4 KB
    __shared__ float xs[64 * 68];           // stride 68 -> 2-way banks (free)
    const int t = threadIdx.x;
    for (int i = t * 4; i < HID * NC; i += 256 * 4)
        *(float4*)&Ws[i] = *(const float4*)&W2[i];
    const int jq = t & 3;
    const int rl = t >> 2;
    const int row0 = blockIdx.x * 64;
    __syncthreads();
    for (int i = t; i < 64 * (HID / 4); i += 256) {
        int rr = i >> 4, cc = i & 15;
        int gr = row0 + rr;
        float4 v = (gr < N_NODES) ? *(const float4*)&hin[(size_t)gr * HID + cc * 4]
                                  : float4{0.f, 0.f, 0.f, 0.f};
        *(float4*)&xs[rr * 68 + cc * 4] = v;
    }
    __syncthreads();
    int r = row0 + rl;
    if (r < N_NODES) {
        float4 acc = {0.f, 0.f, 0.f, 0.f};
        #pragma unroll
        for (int k = 0; k < HID; k += 4) {
            float4 xv = *(float4*)&xs[rl * 68 + k];
            float4 w0 = *(float4*)&Ws[(k + 0) * NC + jq * 4];
            float4 w1 = *(float4*)&Ws[(k + 1) * NC + jq * 4];
            float4 w2 = *(float4*)&Ws[(k + 2) * NC + jq * 4];
            float4 w3 = *(float4*)&Ws[(k + 3) * NC + jq * 4];
            GEMM_STEP(acc, xv)
        }
        float ns = norm_src[r];
        acc.x *= ns; acc.y *= ns; acc.z *= ns; acc.w *= ns;
        *(float4*)&h2[(size_t)r * NC + jq * 4] = acc;
    }
}

// ---------------- agg2 + softmax: 4 lanes/node, float4, 4-edge unroll --------
__global__ __launch_bounds__(256) void k_agg2(
        const int* __restrict__ row_start, const int* __restrict__ csr_src,
        const float* __restrict__ h2, const float* __restrict__ nd,
        const float* __restrict__ b2, float* __restrict__ out) {
    int t = threadIdx.x;
    int node = blockIdx.x * 64 + (t >> 2);
    int sub = t & 3;                     // feats sub*4..+3
    if (node >= N_NODES) return;
    int beg = row_start[node], end = row_start[node + 1];
    float4 acc = {0.f, 0.f, 0.f, 0.f};
    int p = beg;
    for (; p + 4 <= end; p += 4) {
        int s0 = csr_src[p + 0], s1 = csr_src[p + 1];
        int s2 = csr_src[p + 2], s3 = csr_src[p + 3];
        float4 a0 = *(const float4*)&h2[(size_t)s0 * NC + sub * 4];
        float4 a1 = *(const float4*)&h2[(size_t)s1 * NC + sub * 4];
        float4 a2 = *(const float4*)&h2[(size_t)s2 * NC + sub * 4];
        float4 a3 = *(const float4*)&h2[(size_t)s3 * NC + sub * 4];
        acc.x += a0.x + a1.x + a2.x + a3.x;
        acc.y += a0.y + a1.y + a2.y + a3.y;
        acc.z += a0.z + a1.z + a2.z + a3.z;
        acc.w += a0.w + a1.w + a2.w + a3.w;
    }
    for (; p < end; ++p) {
        int s = csr_src[p];
        float4 a = *(const float4*)&h2[(size_t)s * NC + sub * 4];
        acc.x += a.x; acc.y += a.y; acc.z += a.z; acc.w += a.w;
    }
    float n = nd[node];
    float4 bb = *(const float4*)&b2[sub * 4];
    float4 vv;
    vv.x = acc.x * n + bb.x;
    vv.y = acc.y * n + bb.y;
    vv.z = acc.z * n + bb.z;
    vv.w = acc.w * n + bb.w;
    float m = fmaxf(fmaxf(vv.x, vv.y), fmaxf(vv.z, vv.w));
    m = fmaxf(m, __shfl_xor(m, 1, 4));
    m = fmaxf(m, __shfl_xor(m, 2, 4));
    float e0 = __expf(vv.x - m), e1 = __expf(vv.y - m);
    float e2 = __expf(vv.z - m), e3 = __expf(vv.w - m);
    float s = e0 + e1 + e2 + e3;
    s += __shfl_xor(s, 1, 4);
    s += __shfl_xor(s, 2, 4);
    float inv = 1.0f / s;
    float4 o = { e0 * inv, e1 * inv, e2 * inv, e3 * inv };
    *(float4*)&out[(size_t)node * NC + sub * 4] = o;
}

extern "C" void kernel_launch(void* const* d_in, const int* in_sizes, int n_in,
                              void* d_out, int out_size, void* d_ws, size_t ws_size,
                              hipStream_t stream) {
    const float* x   = (const float*)d_in[0];
    const int*   src = (const int*)  d_in[1];
    const int*   dst = (const int*)  d_in[2];
    const float* W1  = (const float*)d_in[3];
    const float* b1  = (const float*)d_in[4];
    const float* W2  = (const float*)d_in[5];
    const float* b2  = (const float*)d_in[6];
    float* out = (float*)d_out;

    // ws layout (4-byte words), N=100000, E=1.6M:
    //   [0,N) norm_src | [N,2N) norm_dst
    //   [2N,34N)   h1 fp16 (64N halves); h2 fp32 (16N) aliases after agg1
    //   [66N,130N) h1r fp32; ebufD (E words)+ebufS (E bytes) alias before agg1
    //   [130N,131N] row_start (N+1)
    //   [131N+8 ..)  bucketStart | gHist | csr_src
    const size_t N = N_NODES;
    float* ws       = (float*)d_ws;
    int*   wsI      = (int*)d_ws;
    float* norm_src = ws;
    float* norm_dst = ws + N;
    __half* h1h     = (__half*)(ws + 2 * N);   // 64N halves = 32N words
    float* h2       = ws + 2 * N;              // alias (h1 dead after agg1)
    float* h1r      = ws + 66 * N;
    unsigned int*  ebufD = (unsigned int*)(wsI + 66 * N);            // E words
    unsigned char* ebufS = (unsigned char*)(wsI + 66 * N + N_EDGES); // E bytes
    int*   row_st   = wsI + 130 * N;
    int*   bstart   = wsI + 131 * N + 8;
    int*   gHist    = wsI + 131 * N + 800;
    int*   csr_src  = wsI + 131 * N + 800 + NBLK_P * NB_ALL;

    k_p1  <<<NBLK_P, 256, 0, stream>>>(src, dst, gHist);
    k_p2  <<<1, 1024, 0, stream>>>(gHist, bstart);
    k_p3  <<<NBLK_P, 256, 0, stream>>>(src, dst, gHist, ebufD, ebufS);
    k_bcsr<<<NB_D, 256, 0, stream>>>(bstart, ebufD, row_st, norm_dst, csr_src);
    k_bdeg<<<NB_D, 256, 0, stream>>>(bstart, ebufS, norm_src);
    k_gemm1<<<(N_NODES + 63) / 64, 256, 0, stream>>>(x, W1, norm_src, h1h);
    k_agg1<<<(N_NODES + 15) / 16, 256, 0, stream>>>(row_st, csr_src, h1h,
                                                    norm_dst, b1, h1r);
    k_gemm2<<<(N_NODES + 63) / 64, 256, 0, stream>>>(h1r, W2, norm_src, h2);
    k_agg2<<<(N_NODES + 63) / 64, 256, 0, stream>>>(row_st, csr_src, h2,
                                                    norm_dst, b2, out);
}

// Round 7
// 296.685 us; speedup vs baseline: 2.9777x; 1.2174x over previous
//
#include <hip/hip_runtime.h>
#include <hip/hip_fp16.h>
#include <math.h>

// GCN 2-layer, fp32 compute. Round 7: gemm1 launch_bounds(256,2) — R6's
// (256,4) forced a 64-VGPR allocation and re-introduced spills (WRITE 157 MB).
// The kernel needs ~116 VGPR (R4 evidence); cap 256, occupancy lands at
// 4 blocks/CU via the VGPR limit. h1 fp16 (verified absmax 4.9e-4).

constexpr int N_NODES = 100000;
constexpr int N_EDGES = 1600000;
constexpr int IN_F    = 128;
constexpr int HID     = 64;
constexpr int NC      = 16;

constexpr int NBLK_P  = 128;                 // partition blocks
constexpr int EPB     = N_EDGES / NBLK_P;    // 12500 edges per partition block
constexpr int NB_D    = 391;                 // dst buckets (256 nodes each)
constexpr int NB_ALL  = 2 * NB_D;            // 782: [0,391) dst, [391,782) src

// ---------------- p1: per-block bucket histogram (both keys) ----------------
__global__ __launch_bounds__(256) void k_p1(const int* __restrict__ src,
                                            const int* __restrict__ dst,
                                            int* __restrict__ gHist) {
    __shared__ int hist[NB_ALL];
    const int t = threadIdx.x, b = blockIdx.x;
    for (int i = t; i < NB_ALL; i += 256) hist[i] = 0;
    __syncthreads();
    const int beg = b * EPB, end = beg + EPB;
    for (int i = beg + t; i < end; i += 256) {
        atomicAdd(&hist[dst[i] >> 8], 1);
        atomicAdd(&hist[NB_D + (src[i] >> 8)], 1);
    }
    __syncthreads();
    for (int i = t; i < NB_ALL; i += 256)
        gHist[b * NB_ALL + i] = hist[i];     // coalesced
}

// ---------------- p2: column scan -> cursors (in place) + bucket starts ------
__global__ __launch_bounds__(1024) void k_p2(int* __restrict__ gHist,
                                             int* __restrict__ bucketStart) {
    const int t = threadIdx.x;               // 1024 threads, 782 active columns
    int total = 0;
    if (t < NB_ALL) {
        #pragma unroll 8
        for (int blk = 0; blk < NBLK_P; ++blk) {
            int idx = blk * NB_ALL + t;      // coalesced across threads
            int v = gHist[idx];
            gHist[idx] = total;              // local exclusive prefix
            total += v;
        }
    }
    int v = total;
    int lane = t & 63, wid = t >> 6;
    #pragma unroll
    for (int d = 1; d < 64; d <<= 1) { int u = __shfl_up(v, d, 64); if (lane >= d) v += u; }
    __shared__ int wsum[16];
    if (lane == 63) wsum[wid] = v;
    __syncthreads();
    int woff = 0;
    for (int w = 0; w < wid; ++w) woff += wsum[w];
    int colStart = woff + v - total;         // exclusive
    if (t < NB_ALL) {
        bucketStart[t] = colStart;
        if (t == NB_ALL - 1) bucketStart[NB_ALL] = colStart + total;  // = 2E
        #pragma unroll 8
        for (int blk = 0; blk < NBLK_P; ++blk)
            gHist[blk * NB_ALL + t] += colStart;   // now global cursors
    }
}

// ---------------- p3: scatter edges into buckets (LDS cursors) ----------------
__global__ __launch_bounds__(256) void k_p3(const int* __restrict__ src,
                                            const int* __restrict__ dst,
                                            const int* __restrict__ gCursor,
                                            unsigned int* __restrict__ ebufD,
                                            unsigned char* __restrict__ ebufS) {
    __shared__ int curs[NB_ALL];
    const int t = threadIdx.x, b = blockIdx.x;
    for (int i = t; i < NB_ALL; i += 256) curs[i] = gCursor[b * NB_ALL + i];
    __syncthreads();
    const int beg = b * EPB, end = beg + EPB;
    for (int i = beg + t; i < end; i += 256) {
        int d = dst[i], s = src[i];
        int pD = atomicAdd(&curs[d >> 8], 1);
        ebufD[pD] = ((unsigned)(d & 255) << 17) | (unsigned)s;
        int pS = atomicAdd(&curs[NB_D + (s >> 8)], 1);
        ebufS[pS - N_EDGES] = (unsigned char)(s & 255);
    }
}

// ---------------- bcsr: per-bucket CSR build + norm_dst + row_start ----------
__global__ __launch_bounds__(256) void k_bcsr(const int* __restrict__ bucketStart,
                                              const unsigned int* __restrict__ ebufD,
                                              int* __restrict__ row_start,
                                              float* __restrict__ norm_dst,
                                              int* __restrict__ csr_src) {
    __shared__ int cnt[256];
    __shared__ int curs[256];
    __shared__ int wsum[4];
    const int t = threadIdx.x, b = blockIdx.x;
    const int beg = bucketStart[b], end = bucketStart[b + 1];
    cnt[t] = 0;
    __syncthreads();
    for (int i = beg + t; i < end; i += 256)
        atomicAdd(&cnt[ebufD[i] >> 17], 1);
    __syncthreads();
    int x = cnt[t];
    int v = x;
    int lane = t & 63, wid = t >> 6;
    #pragma unroll
    for (int d = 1; d < 64; d <<= 1) { int u = __shfl_up(v, d, 64); if (lane >= d) v += u; }
    if (lane == 63) wsum[wid] = v;
    __syncthreads();
    int woff = 0;
    for (int w = 0; w < wid; ++w) woff += wsum[w];
    int rs = woff + v - x;                   // exclusive prefix
    int node = b * 256 + t;
    if (node <= N_NODES) row_start[node] = beg + rs;
    if (node <  N_NODES) norm_dst[node] = 1.0f / sqrtf(fmaxf((float)x, 1.0f));
    curs[t] = beg + rs;
    __syncthreads();
    for (int i = beg + t; i < end; i += 256) {
        unsigned int e = ebufD[i];
        int pos = atomicAdd(&curs[e >> 17], 1);
        csr_src[pos] = (int)(e & 0x1FFFFu);
    }
}

// ---------------- bdeg: per-bucket src counts -> norm_src ----------------
__global__ __launch_bounds__(256) void k_bdeg(const int* __restrict__ bucketStart,
                                              const unsigned char* __restrict__ ebufS,
                                              float* __restrict__ norm_src) {
    __shared__ int cnt[256];
    const int t = threadIdx.x, b = blockIdx.x;
    const int beg = bucketStart[NB_D + b] - N_EDGES;
    const int end = bucketStart[NB_D + b + 1] - N_EDGES;
    cnt[t] = 0;
    __syncthreads();
    for (int i = beg + t; i < end; i += 256)
        atomicAdd(&cnt[ebufS[i]], 1);
    __syncthreads();
    int node = b * 256 + t;
    if (node < N_NODES)
        norm_src[node] = 1.0f / sqrtf(fmaxf((float)cnt[t], 1.0f));
}

#define GEMM_STEP(accr, xvr) \
    accr.x += xvr.x*w0.x + xvr.y*w1.x + xvr.z*w2.x + xvr.w*w3.x; \
    accr.y += xvr.x*w0.y + xvr.y*w1.y + xvr.z*w2.y + xvr.w*w3.y; \
    accr.z += xvr.x*w0.z + xvr.y*w1.z + xvr.z*w2.z + xvr.w*w3.z; \
    accr.w += xvr.x*w0.w + xvr.y*w1.w + xvr.z*w2.w + xvr.w*w3.w;

// ---------------- GEMM1: 64x64 tile, K-sliced staging (32 per slice) ---------
// LDS 17.2 KB; kh loop NOT unrolled (R5: full unroll -> 256 VGPR + spill).
// launch_bounds(256,2): VGPR cap 256, natural alloc ~116 (R4 evidence) ->
// 4 blocks/CU via VGPR limit, no spill. R6's (256,4) forced 64 VGPR + spill.
__global__ __launch_bounds__(256, 2) void k_gemm1(
        const float* __restrict__ x, const float* __restrict__ W1,
        const float* __restrict__ norm_src, __half* __restrict__ h1h) {
    __shared__ float Ws[32 * HID];       // 8 KB
    __shared__ float xs[64 * 36];        // 9.2 KB, stride 36 -> 2-way banks (free)
    const int t = threadIdx.x;
    const int cg = t & 15;               // cols cg*4..+3
    const int rg = t >> 4;               // rows rg*4..+3
    const int row0 = blockIdx.x * 64;
    float4 acc0 = {0,0,0,0}, acc1 = {0,0,0,0}, acc2 = {0,0,0,0}, acc3 = {0,0,0,0};
    #pragma unroll 1
    for (int kh = 0; kh < 4; ++kh) {     // 4 K-slices of 32
        __syncthreads();
        for (int i = t; i < 512; i += 256) {          // x slice: 64r x 32k
            int rr = i >> 3, cc = i & 7;
            int gr = row0 + rr;
            float4 v = (gr < N_NODES)
                ? *(const float4*)&x[(size_t)gr * IN_F + kh * 32 + cc * 4]
                : float4{0.f, 0.f, 0.f, 0.f};
            *(float4*)&xs[rr * 36 + cc * 4] = v;
        }
        for (int i = t; i < 512; i += 256) {          // W slice: 32k x 64c
            int kr = i >> 4, kc = i & 15;
            *(float4*)&Ws[kr * HID + kc * 4] =
                *(const float4*)&W1[(size_t)(kh * 32 + kr) * HID + kc * 4];
        }
        __syncthreads();
        #pragma unroll
        for (int k = 0; k < 32; k += 4) {
            float4 xv0 = *(float4*)&xs[(rg * 4 + 0) * 36 + k];
            float4 xv1 = *(float4*)&xs[(rg * 4 + 1) * 36 + k];
            float4 xv2 = *(float4*)&xs[(rg * 4 + 2) * 36 + k];
            float4 xv3 = *(float4*)&xs[(rg * 4 + 3) * 36 + k];
            float4 w0 = *(float4*)&Ws[(k + 0) * HID + cg * 4];
            float4 w1 = *(float4*)&Ws[(k + 1) * HID + cg * 4];
            float4 w2 = *(float4*)&Ws[(k + 2) * HID + cg * 4];
            float4 w3 = *(float4*)&Ws[(k + 3) * HID + cg * 4];
            GEMM_STEP(acc0, xv0)
            GEMM_STEP(acc1, xv1)
            GEMM_STEP(acc2, xv2)
            GEMM_STEP(acc3, xv3)
        }
    }
    const int r0 = row0 + rg * 4;
    #pragma unroll
    for (int r = 0; r < 4; ++r) {
        int rr = r0 + r;
        if (rr < N_NODES) {
            float4 a = (r == 0) ? acc0 : (r == 1) ? acc1 : (r == 2) ? acc2 : acc3;
            float ns = norm_src[rr];
            float2 pk;
            *(__half2*)&pk.x = __floats2half2_rn(a.x * ns, a.y * ns);
            *(__half2*)&pk.y = __floats2half2_rn(a.z * ns, a.w * ns);
            *(float2*)&h1h[(size_t)rr * HID + cg * 4] = pk;   // 8B store
        }
    }
}

// ---------------- agg1: 16 lanes/node, fp16 gathers, 8-edge unroll -----------
__global__ __launch_bounds__(256) void k_agg1(
        const int* __restrict__ row_start, const int* __restrict__ csr_src,
        const __half* __restrict__ h1h, const float* __restrict__ nd,
        const float* __restrict__ b1, float* __restrict__ h1r) {
    int node = blockIdx.x * 16 + (threadIdx.x >> 4);
    int q = threadIdx.x & 15;            // feat quad
    if (node >= N_NODES) return;
    int beg = row_start[node], end = row_start[node + 1];
    float4 acc = {0.f, 0.f, 0.f, 0.f};
    int p = beg;
    for (; p + 8 <= end; p += 8) {
        float2 g[8];
        #pragma unroll
        for (int u = 0; u < 8; ++u) {
            int s = csr_src[p + u];
            g[u] = *(const float2*)&h1h[(size_t)s * HID + q * 4];
        }
        #pragma unroll
        for (int u = 0; u < 8; ++u) {
            float2 f0 = __half22float2(*(__half2*)&g[u].x);
            float2 f1 = __half22float2(*(__half2*)&g[u].y);
            acc.x += f0.x; acc.y += f0.y; acc.z += f1.x; acc.w += f1.y;
        }
    }
    for (; p < end; ++p) {
        int s = csr_src[p];
        float2 raw = *(const float2*)&h1h[(size_t)s * HID + q * 4];
        float2 f0 = __half22float2(*(__half2*)&raw.x);
        float2 f1 = __half22float2(*(__half2*)&raw.y);
        acc.x += f0.x; acc.y += f0.y; acc.z += f1.x; acc.w += f1.y;
    }
    float n = nd[node];
    float4 bb = *(const float4*)&b1[q * 4];
    float4 o;
    o.x = fmaxf(acc.x * n + bb.x, 0.f);
    o.y = fmaxf(acc.y * n + bb.y, 0.f);
    o.z = fmaxf(acc.z * n + bb.z, 0.f);
    o.w = fmaxf(acc.w * n + bb.w, 0.f);
    *(float4*)&h1r[(size_t)node * HID + q * 4] = o;
}

// ---------------- GEMM2: 64-row tiles ----------------
__global__ __launch_bounds__(256) void k_gemm2(
        const float* __restrict__ hin, const float* __restrict__ W2,
        const float* __restrict__ norm_src, float* __restrict__ h2) {
    __shared__ float Ws[HID * NC];          // 4 KB
    __shared__ float xs[64 * 68];           // stride 68 -> 2-way banks (free)
    const int t = threadIdx.x;
    for (int i = t * 4; i < HID * NC; i += 256 * 4)
        *(float4*)&Ws[i] = *(const float4*)&W2[i];
    const int jq = t & 3;
    const int rl = t >> 2;
    const int row0 = blockIdx.x * 64;
    __syncthreads();
    for (int i = t; i < 64 * (HID / 4); i += 256) {
        int rr = i >> 4, cc = i & 15;
        int gr = row0 + rr;
        float4 v = (gr < N_NODES) ? *(const float4*)&hin[(size_t)gr * HID + cc * 4]
                                  : float4{0.f, 0.f, 0.f, 0.f};
        *(float4*)&xs[rr * 68 + cc * 4] = v;
    }
    __syncthreads();
    int r = row0 + rl;
    if (r < N_NODES) {
        float4 acc = {0.f, 0.f, 0.f, 0.f};
        #pragma unroll
        for (int k = 0; k < HID; k += 4) {
            float4 xv = *(float4*)&xs[rl * 68 + k];
            float4 w0 = *(float4*)&Ws[(k + 0) * NC + jq * 4];
            float4 w1 = *(float4*)&Ws[(k + 1) * NC + jq * 4];
            float4 w2 = *(float4*)&Ws[(k + 2) * NC + jq * 4];
            float4 w3 = *(float4*)&Ws[(k + 3) * NC + jq * 4];
            GEMM_STEP(acc, xv)
        }
        float ns = norm_src[r];
        acc.x *= ns; acc.y *= ns; acc.z *= ns; acc.w *= ns;
        *(float4*)&h2[(size_t)r * NC + jq * 4] = acc;
    }
}

// ---------------- agg2 + softmax: 4 lanes/node, float4, 4-edge unroll --------
__global__ __launch_bounds__(256) void k_agg2(
        const int* __restrict__ row_start, const int* __restrict__ csr_src,
        const float* __restrict__ h2, const float* __restrict__ nd,
        const float* __restrict__ b2, float* __restrict__ out) {
    int t = threadIdx.x;
    int node = blockIdx.x * 64 + (t >> 2);
    int sub = t & 3;                     // feats sub*4..+3
    if (node >= N_NODES) return;
    int beg = row_start[node], end = row_start[node + 1];
    float4 acc = {0.f, 0.f, 0.f, 0.f};
    int p = beg;
    for (; p + 4 <= end; p += 4) {
        int s0 = csr_src[p + 0], s1 = csr_src[p + 1];
        int s2 = csr_src[p + 2], s3 = csr_src[p + 3];
        float4 a0 = *(const float4*)&h2[(size_t)s0 * NC + sub * 4];
        float4 a1 = *(const float4*)&h2[(size_t)s1 * NC + sub * 4];
        float4 a2 = *(const float4*)&h2[(size_t)s2 * NC + sub * 4];
        float4 a3 = *(const float4*)&h2[(size_t)s3 * NC + sub * 4];
        acc.x += a0.x + a1.x + a2.x + a3.x;
        acc.y += a0.y + a1.y + a2.y + a3.y;
        acc.z += a0.z + a1.z + a2.z + a3.z;
        acc.w += a0.w + a1.w + a2.w + a3.w;
    }
    for (; p < end; ++p) {
        int s = csr_src[p];
        float4 a = *(const float4*)&h2[(size_t)s * NC + sub * 4];
        acc.x += a.x; acc.y += a.y; acc.z += a.z; acc.w += a.w;
    }
    float n = nd[node];
    float4 bb = *(const float4*)&b2[sub * 4];
    float4 vv;
    vv.x = acc.x * n + bb.x;
    vv.y = acc.y * n + bb.y;
    vv.z = acc.z * n + bb.z;
    vv.w = acc.w * n + bb.w;
    float m = fmaxf(fmaxf(vv.x, vv.y), fmaxf(vv.z, vv.w));
    m = fmaxf(m, __shfl_xor(m, 1, 4));
    m = fmaxf(m, __shfl_xor(m, 2, 4));
    float e0 = __expf(vv.x - m), e1 = __expf(vv.y - m);
    float e2 = __expf(vv.z - m), e3 = __expf(vv.w - m);
    float s = e0 + e1 + e2 + e3;
    s += __shfl_xor(s, 1, 4);
    s += __shfl_xor(s, 2, 4);
    float inv = 1.0f / s;
    float4 o = { e0 * inv, e1 * inv, e2 * inv, e3 * inv };
    *(float4*)&out[(size_t)node * NC + sub * 4] = o;
}

extern "C" void kernel_launch(void* const* d_in, const int* in_sizes, int n_in,
                              void* d_out, int out_size, void* d_ws, size_t ws_size,
                              hipStream_t stream) {
    const float* x   = (const float*)d_in[0];
    const int*   src = (const int*)  d_in[1];
    const int*   dst = (const int*)  d_in[2];
    const float* W1  = (const float*)d_in[3];
    const float* b1  = (const float*)d_in[4];
    const float* W2  = (const float*)d_in[5];
    const float* b2  = (const float*)d_in[6];
    float* out = (float*)d_out;

    // ws layout (4-byte words), N=100000, E=1.6M:
    //   [0,N) norm_src | [N,2N) norm_dst
    //   [2N,34N)   h1 fp16 (64N halves); h2 fp32 (16N) aliases after agg1
    //   [66N,130N) h1r fp32; ebufD (E words)+ebufS (E bytes) alias before agg1
    //   [130N,131N] row_start (N+1)
    //   [131N+8 ..)  bucketStart | gHist | csr_src
    const size_t N = N_NODES;
    float* ws       = (float*)d_ws;
    int*   wsI      = (int*)d_ws;
    float* norm_src = ws;
    float* norm_dst = ws + N;
    __half* h1h     = (__half*)(ws + 2 * N);   // 64N halves = 32N words
    float* h2       = ws + 2 * N;              // alias (h1 dead after agg1)
    float* h1r      = ws + 66 * N;
    unsigned int*  ebufD = (unsigned int*)(wsI + 66 * N);            // E words
    unsigned char* ebufS = (unsigned char*)(wsI + 66 * N + N_EDGES); // E bytes
    int*   row_st   = wsI + 130 * N;
    int*   bstart   = wsI + 131 * N + 8;
    int*   gHist    = wsI + 131 * N + 800;
    int*   csr_src  = wsI + 131 * N + 800 + NBLK_P * NB_ALL;

    k_p1  <<<NBLK_P, 256, 0, stream>>>(src, dst, gHist);
    k_p2  <<<1, 1024, 0, stream>>>(gHist, bstart);
    k_p3  <<<NBLK_P, 256, 0, stream>>>(src, dst, gHist, ebufD, ebufS);
    k_bcsr<<<NB_D, 256, 0, stream>>>(bstart, ebufD, row_st, norm_dst, csr_src);
    k_bdeg<<<NB_D, 256, 0, stream>>>(bstart, ebufS, norm_src);
    k_gemm1<<<(N_NODES + 63) / 64, 256, 0, stream>>>(x, W1, norm_src, h1h);
    k_agg1<<<(N_NODES + 15) / 16, 256, 0, stream>>>(row_st, csr_src, h1h,
                                                    norm_dst, b1, h1r);
    k_gemm2<<<(N_NODES + 63) / 64, 256, 0, stream>>>(h1r, W2, norm_src, h2);
    k_agg2<<<(N_NODES + 63) / 64, 256, 0, stream>>>(row_st, csr_src, h2,
                                                    norm_dst, b2, out);
}

// Round 8
// 274.035 us; speedup vs baseline: 3.2238x; 1.0827x over previous
//
#include <hip/hip_runtime.h>
#include <hip/hip_fp16.h>
#include <math.h>

// GCN 2-layer. Round 8: gemm1 -> MFMA f16 (R7 showed the VALU gemm is
// LDS-read-throughput bound at ~47us; MFMA cuts LDS->reg traffic ~12x).
// h2 stored fp16 (halves agg2 gather bytes). h1 fp16 (verified since R5).

constexpr int N_NODES = 100000;
constexpr int N_EDGES = 1600000;
constexpr int IN_F    = 128;
constexpr int HID     = 64;
constexpr int NC      = 16;

constexpr int NBLK_P  = 128;                 // partition blocks
constexpr int EPB     = N_EDGES / NBLK_P;    // 12500 edges per partition block
constexpr int NB_D    = 391;                 // dst buckets (256 nodes each)
constexpr int NB_ALL  = 2 * NB_D;            // 782: [0,391) dst, [391,782) src

typedef _Float16 f16x8 __attribute__((ext_vector_type(8)));
typedef _Float16 f16x4 __attribute__((ext_vector_type(4)));
typedef float    f32x4 __attribute__((ext_vector_type(4)));

// ---------------- p1: per-block bucket histogram (both keys) ----------------
__global__ __launch_bounds__(256) void k_p1(const int* __restrict__ src,
                                            const int* __restrict__ dst,
                                            int* __restrict__ gHist) {
    __shared__ int hist[NB_ALL];
    const int t = threadIdx.x, b = blockIdx.x;
    for (int i = t; i < NB_ALL; i += 256) hist[i] = 0;
    __syncthreads();
    const int beg = b * EPB, end = beg + EPB;
    for (int i = beg + t; i < end; i += 256) {
        atomicAdd(&hist[dst[i] >> 8], 1);
        atomicAdd(&hist[NB_D + (src[i] >> 8)], 1);
    }
    __syncthreads();
    for (int i = t; i < NB_ALL; i += 256)
        gHist[b * NB_ALL + i] = hist[i];     // coalesced
}

// ---------------- p2: column scan -> cursors (in place) + bucket starts ------
__global__ __launch_bounds__(1024) void k_p2(int* __restrict__ gHist,
                                             int* __restrict__ bucketStart) {
    const int t = threadIdx.x;               // 1024 threads, 782 active columns
    int total = 0;
    if (t < NB_ALL) {
        #pragma unroll 8
        for (int blk = 0; blk < NBLK_P; ++blk) {
            int idx = blk * NB_ALL + t;      // coalesced across threads
            int v = gHist[idx];
            gHist[idx] = total;              // local exclusive prefix
            total += v;
        }
    }
    int v = total;
    int lane = t & 63, wid = t >> 6;
    #pragma unroll
    for (int d = 1; d < 64; d <<= 1) { int u = __shfl_up(v, d, 64); if (lane >= d) v += u; }
    __shared__ int wsum[16];
    if (lane == 63) wsum[wid] = v;
    __syncthreads();
    int woff = 0;
    for (int w = 0; w < wid; ++w) woff += wsum[w];
    int colStart = woff + v - total;         // exclusive
    if (t < NB_ALL) {
        bucketStart[t] = colStart;
        if (t == NB_ALL - 1) bucketStart[NB_ALL] = colStart + total;  // = 2E
        #pragma unroll 8
        for (int blk = 0; blk < NBLK_P; ++blk)
            gHist[blk * NB_ALL + t] += colStart;   // now global cursors
    }
}

// ---------------- p3: scatter edges into buckets (LDS cursors) ----------------
__global__ __launch_bounds__(256) void k_p3(const int* __restrict__ src,
                                            const int* __restrict__ dst,
                                            const int* __restrict__ gCursor,
                                            unsigned int* __restrict__ ebufD,
                                            unsigned char* __restrict__ ebufS) {
    __shared__ int curs[NB_ALL];
    const int t = threadIdx.x, b = blockIdx.x;
    for (int i = t; i < NB_ALL; i += 256) curs[i] = gCursor[b * NB_ALL + i];
    __syncthreads();
    const int beg = b * EPB, end = beg + EPB;
    for (int i = beg + t; i < end; i += 256) {
        int d = dst[i], s = src[i];
        int pD = atomicAdd(&curs[d >> 8], 1);
        ebufD[pD] = ((unsigned)(d & 255) << 17) | (unsigned)s;
        int pS = atomicAdd(&curs[NB_D + (s >> 8)], 1);
        ebufS[pS - N_EDGES] = (unsigned char)(s & 255);
    }
}

// ---------------- bcsr: per-bucket CSR build + norm_dst + row_start ----------
__global__ __launch_bounds__(256) void k_bcsr(const int* __restrict__ bucketStart,
                                              const unsigned int* __restrict__ ebufD,
                                              int* __restrict__ row_start,
                                              float* __restrict__ norm_dst,
                                              int* __restrict__ csr_src) {
    __shared__ int cnt[256];
    __shared__ int curs[256];
    __shared__ int wsum[4];
    const int t = threadIdx.x, b = blockIdx.x;
    const int beg = bucketStart[b], end = bucketStart[b + 1];
    cnt[t] = 0;
    __syncthreads();
    for (int i = beg + t; i < end; i += 256)
        atomicAdd(&cnt[ebufD[i] >> 17], 1);
    __syncthreads();
    int x = cnt[t];
    int v = x;
    int lane = t & 63, wid = t >> 6;
    #pragma unroll
    for (int d = 1; d < 64; d <<= 1) { int u = __shfl_up(v, d, 64); if (lane >= d) v += u; }
    if (lane == 63) wsum[wid] = v;
    __syncthreads();
    int woff = 0;
    for (int w = 0; w < wid; ++w) woff += wsum[w];
    int rs = woff + v - x;                   // exclusive prefix
    int node = b * 256 + t;
    if (node <= N_NODES) row_start[node] = beg + rs;
    if (node <  N_NODES) norm_dst[node] = 1.0f / sqrtf(fmaxf((float)x, 1.0f));
    curs[t] = beg + rs;
    __syncthreads();
    for (int i = beg + t; i < end; i += 256) {
        unsigned int e = ebufD[i];
        int pos = atomicAdd(&curs[e >> 17], 1);
        csr_src[pos] = (int)(e & 0x1FFFFu);
    }
}

// ---------------- bdeg: per-bucket src counts -> norm_src ----------------
__global__ __launch_bounds__(256) void k_bdeg(const int* __restrict__ bucketStart,
                                              const unsigned char* __restrict__ ebufS,
                                              float* __restrict__ norm_src) {
    __shared__ int cnt[256];
    const int t = threadIdx.x, b = blockIdx.x;
    const int beg = bucketStart[NB_D + b] - N_EDGES;
    const int end = bucketStart[NB_D + b + 1] - N_EDGES;
    cnt[t] = 0;
    __syncthreads();
    for (int i = beg + t; i < end; i += 256)
        atomicAdd(&cnt[ebufS[i]], 1);
    __syncthreads();
    int node = b * 256 + t;
    if (node < N_NODES)
        norm_src[node] = 1.0f / sqrtf(fmaxf((float)cnt[t], 1.0f));
}

// ---------------- GEMM1 (MFMA f16): h1h = (x @ W1) * ns, fp16 out -----------
// Block: 256 thr = 4 waves; tile 64 rows x 64 cols; K=128 staged whole.
// LDS: xh[64][136] f16 (17408 B) + wt[64][136] f16 transposed (17408 B).
// Fragment layouts (measured, guide §3): A[m=lane&15][k=(lane>>4)*8+j];
// B[k=(lane>>4)*8+j][n=lane&15] (read from wt[n][k], contiguous);
// C/D col=lane&15, row=(lane>>4)*4+reg.
constexpr int PADK = 136;   // row stride in halves (272 B, 16-B aligned)
__global__ __launch_bounds__(256) void k_gemm1(
        const float* __restrict__ x, const float* __restrict__ W1,
        const float* __restrict__ norm_src, __half* __restrict__ h1h) {
    __shared__ _Float16 xh[64 * PADK];
    __shared__ _Float16 wt[64 * PADK];
    const int t = threadIdx.x;
    const int row0 = blockIdx.x * 64;
    // stage x (fp32 -> fp16): 64 rows x 32 float4-chunks
    for (int i = t; i < 64 * 32; i += 256) {
        int c4 = i & 31, rr = i >> 5;
        int gr = row0 + rr;
        float4 v = (gr < N_NODES) ? *(const float4*)&x[(size_t)gr * IN_F + c4 * 4]
                                  : float4{0.f, 0.f, 0.f, 0.f};
        f16x4 hv;
        hv[0] = (_Float16)v.x; hv[1] = (_Float16)v.y;
        hv[2] = (_Float16)v.z; hv[3] = (_Float16)v.w;
        *(f16x4*)&xh[rr * PADK + c4 * 4] = hv;
    }
    // stage W1 transposed: wt[n][k]; coalesced reads of W1[k][n]
    for (int i = t; i < 64 * 32; i += 256) {
        int n = i & 63, kq = i >> 6;         // kq: 0..31 -> k0 = kq*4
        int k0 = kq * 4;
        f16x4 hv;
        #pragma unroll
        for (int j = 0; j < 4; ++j)
            hv[j] = (_Float16)W1[(size_t)(k0 + j) * HID + n];
        *(f16x4*)&wt[n * PADK + k0] = hv;
    }
    __syncthreads();
    const int w = t >> 6;                    // wave -> 16-row m-strip
    const int l = t & 63;
    const int m = l & 15, q = l >> 4;
    f32x4 acc0 = {0,0,0,0}, acc1 = {0,0,0,0}, acc2 = {0,0,0,0}, acc3 = {0,0,0,0};
    #pragma unroll
    for (int kc = 0; kc < 4; ++kc) {         // 4 K-chunks of 32
        f16x8 af = *(const f16x8*)&xh[(16 * w + m) * PADK + kc * 32 + q * 8];
        f16x8 b0 = *(const f16x8*)&wt[( 0 + m) * PADK + kc * 32 + q * 8];
        f16x8 b1 = *(const f16x8*)&wt[(16 + m) * PADK + kc * 32 + q * 8];
        f16x8 b2 = *(const f16x8*)&wt[(32 + m) * PADK + kc * 32 + q * 8];
        f16x8 b3 = *(const f16x8*)&wt[(48 + m) * PADK + kc * 32 + q * 8];
        acc0 = __builtin_amdgcn_mfma_f32_16x16x32_f16(af, b0, acc0, 0, 0, 0);
        acc1 = __builtin_amdgcn_mfma_f32_16x16x32_f16(af, b1, acc1, 0, 0, 0);
        acc2 = __builtin_amdgcn_mfma_f32_16x16x32_f16(af, b2, acc2, 0, 0, 0);
        acc3 = __builtin_amdgcn_mfma_f32_16x16x32_f16(af, b3, acc3, 0, 0, 0);
    }
    _Float16* out = (_Float16*)h1h;
    #pragma unroll
    for (int r = 0; r < 4; ++r) {
        int row_g = row0 + 16 * w + q * 4 + r;
        if (row_g < N_NODES) {
            float ns = norm_src[row_g];
            size_t base = (size_t)row_g * HID + m;
            out[base +  0] = (_Float16)(acc0[r] * ns);
            out[base + 16] = (_Float16)(acc1[r] * ns);
            out[base + 32] = (_Float16)(acc2[r] * ns);
            out[base + 48] = (_Float16)(acc3[r] * ns);
        }
    }
}

// ---------------- agg1: 16 lanes/node, fp16 gathers, 8-edge unroll -----------
__global__ __launch_bounds__(256) void k_agg1(
        const int* __restrict__ row_start, const int* __restrict__ csr_src,
        const __half* __restrict__ h1h, const float* __restrict__ nd,
        const float* __restrict__ b1, float* __restrict__ h1r) {
    int node = blockIdx.x * 16 + (threadIdx.x >> 4);
    int q = threadIdx.x & 15;            // feat quad
    if (node >= N_NODES) return;
    int beg = row_start[node], end = row_start[node + 1];
    float4 acc = {0.f, 0.f, 0.f, 0.f};
    int p = beg;
    for (; p + 8 <= end; p += 8) {
        float2 g[8];
        #pragma unroll
        for (int u = 0; u < 8; ++u) {
            int s = csr_src[p + u];
            g[u] = *(const float2*)&h1h[(size_t)s * HID + q * 4];
        }
        #pragma unroll
        for (int u = 0; u < 8; ++u) {
            float2 f0 = __half22float2(*(__half2*)&g[u].x);
            float2 f1 = __half22float2(*(__half2*)&g[u].y);
            acc.x += f0.x; acc.y += f0.y; acc.z += f1.x; acc.w += f1.y;
        }
    }
    for (; p < end; ++p) {
        int s = csr_src[p];
        float2 raw = *(const float2*)&h1h[(size_t)s * HID + q * 4];
        float2 f0 = __half22float2(*(__half2*)&raw.x);
        float2 f1 = __half22float2(*(__half2*)&raw.y);
        acc.x += f0.x; acc.y += f0.y; acc.z += f1.x; acc.w += f1.y;
    }
    float n = nd[node];
    float4 bb = *(const float4*)&b1[q * 4];
    float4 o;
    o.x = fmaxf(acc.x * n + bb.x, 0.f);
    o.y = fmaxf(acc.y * n + bb.y, 0.f);
    o.z = fmaxf(acc.z * n + bb.z, 0.f);
    o.w = fmaxf(acc.w * n + bb.w, 0.f);
    *(float4*)&h1r[(size_t)node * HID + q * 4] = o;
}

#define GEMM_STEP(accr, xvr) \
    accr.x += xvr.x*w0.x + xvr.y*w1.x + xvr.z*w2.x + xvr.w*w3.x; \
    accr.y += xvr.x*w0.y + xvr.y*w1.y + xvr.z*w2.y + xvr.w*w3.y; \
    accr.z += xvr.x*w0.z + xvr.y*w1.z + xvr.z*w2.z + xvr.w*w3.z; \
    accr.w += xvr.x*w0.w + xvr.y*w1.w + xvr.z*w2.w + xvr.w*w3.w;

// ---------------- GEMM2: 64-row tiles, fp16 output ----------------
__global__ __launch_bounds__(256) void k_gemm2(
        const float* __restrict__ hin, const float* __restrict__ W2,
        const float* __restrict__ norm_src, __half* __restrict__ h2h) {
    __shared__ float Ws[HID * NC];          // 4 KB
    __shared__ float xs[64 * 68];           // stride 68 -> 2-way banks (free)
    const int t = threadIdx.x;
    for (int i = t * 4; i < HID * NC; i += 256 * 4)
        *(float4*)&Ws[i] = *(const float4*)&W2[i];
    const int jq = t & 3;
    const int rl = t >> 2;
    const int row0 = blockIdx.x * 64;
    __syncthreads();
    for (int i = t; i < 64 * (HID / 4); i += 256) {
        int rr = i >> 4, cc = i & 15;
        int gr = row0 + rr;
        float4 v = (gr < N_NODES) ? *(const float4*)&hin[(size_t)gr * HID + cc * 4]
                                  : float4{0.f, 0.f, 0.f, 0.f};
        *(float4*)&xs[rr * 68 + cc * 4] = v;
    }
    __syncthreads();
    int r = row0 + rl;
    if (r < N_NODES) {
        float4 acc = {0.f, 0.f, 0.f, 0.f};
        #pragma unroll
        for (int k = 0; k < HID; k += 4) {
            float4 xv = *(float4*)&xs[rl * 68 + k];
            float4 w0 = *(float4*)&Ws[(k + 0) * NC + jq * 4];
            float4 w1 = *(float4*)&Ws[(k + 1) * NC + jq * 4];
            float4 w2 = *(float4*)&Ws[(k + 2) * NC + jq * 4];
            float4 w3 = *(float4*)&Ws[(k + 3) * NC + jq * 4];
            GEMM_STEP(acc, xv)
        }
        float ns = norm_src[r];
        f16x4 hv;
        hv[0] = (_Float16)(acc.x * ns); hv[1] = (_Float16)(acc.y * ns);
        hv[2] = (_Float16)(acc.z * ns); hv[3] = (_Float16)(acc.w * ns);
        *(f16x4*)&((_Float16*)h2h)[(size_t)r * NC + jq * 4] = hv;
    }
}

// ---------------- agg2 + softmax: 2 lanes/node, fp16 b128 gathers ------------
__global__ __launch_bounds__(256) void k_agg2(
        const int* __restrict__ row_start, const int* __restrict__ csr_src,
        const __half* __restrict__ h2h, const float* __restrict__ nd,
        const float* __restrict__ b2, float* __restrict__ out) {
    int t = threadIdx.x;
    int node = blockIdx.x * 128 + (t >> 1);
    int sub = t & 1;                     // feats sub*8..+7
    if (node >= N_NODES) return;
    int beg = row_start[node], end = row_start[node + 1];
    float acc[8] = {0,0,0,0,0,0,0,0};
    int p = beg;
    for (; p + 4 <= end; p += 4) {
        float4 g[4];
        #pragma unroll
        for (int u = 0; u < 4; ++u) {
            int s = csr_src[p + u];
            g[u] = *(const float4*)&h2h[(size_t)s * NC + sub * 8];
        }
        #pragma unroll
        for (int u = 0; u < 4; ++u) {
            const __half2* hh = (const __half2*)&g[u];
            #pragma unroll
            for (int j = 0; j < 4; ++j) {
                float2 f = __half22float2(hh[j]);
                acc[j * 2 + 0] += f.x; acc[j * 2 + 1] += f.y;
            }
        }
    }
    for (; p < end; ++p) {
        int s = csr_src[p];
        float4 g = *(const float4*)&h2h[(size_t)s * NC + sub * 8];
        const __half2* hh = (const __half2*)&g;
        #pragma unroll
        for (int j = 0; j < 4; ++j) {
            float2 f = __half22float2(hh[j]);
            acc[j * 2 + 0] += f.x; acc[j * 2 + 1] += f.y;
        }
    }
    float n = nd[node];
    float v[8];
    #pragma unroll
    for (int j = 0; j < 8; ++j) v[j] = acc[j] * n + b2[sub * 8 + j];
    float m = v[0];
    #pragma unroll
    for (int j = 1; j < 8; ++j) m = fmaxf(m, v[j]);
    m = fmaxf(m, __shfl_xor(m, 1, 2));
    float e[8]; float s = 0.f;
    #pragma unroll
    for (int j = 0; j < 8; ++j) { e[j] = __expf(v[j] - m); s += e[j]; }
    s += __shfl_xor(s, 1, 2);
    float inv = 1.0f / s;
    float4 o0 = { e[0]*inv, e[1]*inv, e[2]*inv, e[3]*inv };
    float4 o1 = { e[4]*inv, e[5]*inv, e[6]*inv, e[7]*inv };
    *(float4*)&out[(size_t)node * NC + sub * 8 + 0] = o0;
    *(float4*)&out[(size_t)node * NC + sub * 8 + 4] = o1;
}

extern "C" void kernel_launch(void* const* d_in, const int* in_sizes, int n_in,
                              void* d_out, int out_size, void* d_ws, size_t ws_size,
                              hipStream_t stream) {
    const float* x   = (const float*)d_in[0];
    const int*   src = (const int*)  d_in[1];
    const int*   dst = (const int*)  d_in[2];
    const float* W1  = (const float*)d_in[3];
    const float* b1  = (const float*)d_in[4];
    const float* W2  = (const float*)d_in[5];
    const float* b2  = (const float*)d_in[6];
    float* out = (float*)d_out;

    // ws layout (4-byte words), N=100000, E=1.6M:
    //   [0,N) norm_src | [N,2N) norm_dst
    //   [2N,34N)   h1 fp16 (64N halves); h2 fp16 (16N halves) aliases after agg1
    //   [66N,130N) h1r fp32; ebufD (E words)+ebufS (E bytes) alias before agg1
    //   [130N,131N] row_start (N+1)
    //   [131N+8 ..)  bucketStart | gHist | csr_src
    const size_t N = N_NODES;
    float* ws       = (float*)d_ws;
    int*   wsI      = (int*)d_ws;
    float* norm_src = ws;
    float* norm_dst = ws + N;
    __half* h1h     = (__half*)(ws + 2 * N);   // 64N halves
    __half* h2h     = (__half*)(ws + 2 * N);   // alias (h1 dead after agg1)
    float* h1r      = ws + 66 * N;
    unsigned int*  ebufD = (unsigned int*)(wsI + 66 * N);            // E words
    unsigned char* ebufS = (unsigned char*)(wsI + 66 * N + N_EDGES); // E bytes
    int*   row_st   = wsI + 130 * N;
    int*   bstart   = wsI + 131 * N + 8;
    int*   gHist    = wsI + 131 * N + 800;
    int*   csr_src  = wsI + 131 * N + 800 + NBLK_P * NB_ALL;

    k_p1  <<<NBLK_P, 256, 0, stream>>>(src, dst, gHist);
    k_p2  <<<1, 1024, 0, stream>>>(gHist, bstart);
    k_p3  <<<NBLK_P, 256, 0, stream>>>(src, dst, gHist, ebufD, ebufS);
    k_bcsr<<<NB_D, 256, 0, stream>>>(bstart, ebufD, row_st, norm_dst, csr_src);
    k_bdeg<<<NB_D, 256, 0, stream>>>(bstart, ebufS, norm_src);
    k_gemm1<<<(N_NODES + 63) / 64, 256, 0, stream>>>(x, W1, norm_src, h1h);
    k_agg1<<<(N_NODES + 15) / 16, 256, 0, stream>>>(row_st, csr_src, h1h,
                                                    norm_dst, b1, h1r);
    k_gemm2<<<(N_NODES + 63) / 64, 256, 0, stream>>>(h1r, W2, norm_src, h2h);
    k_agg2<<<(N_NODES + 127) / 128, 256, 0, stream>>>(row_st, csr_src, h2h,
                                                      norm_dst, b2, out);
}